// Round 8
// baseline (210.527 us; speedup 1.0000x reference)
//
#include <hip/hip_runtime.h>

#define N_NODES 50000
#define N_EDGES 800000
#define NB      391            // buckets: dst>>7 (128 nodes each), 0..390
#define NSH     8              // shards per bucket (blockIdx&7 ~ XCD)
#define CAP_S   512            // per (bucket,shard) capacity; mean 256, ~16 sigma
#define MAXB    (NSH * CAP_S)  // 4096 max edges staged per bucket

typedef _Float16 h2v __attribute__((ext_vector_type(2)));
typedef _Float16 h8v __attribute__((ext_vector_type(8)));
typedef float    f4v __attribute__((ext_vector_type(4)));

union H2U { h2v h; unsigned u; };   // packed f16 pair <-> dword

// ---------------------------------------------------------------------------
// Prep: cast x -> f16 + pack W1/W2 into MFMA B-fragment order (block 0 only).
// B-frag (16x16x32 f16): lane holds 8 f16 B[k=32kt+(lane>>4)*8+j][n=16nt+(lane&15)].
// ---------------------------------------------------------------------------
__global__ void prep_kernel(const float* __restrict__ x,
                            const float* __restrict__ W1_l,
                            const float* __restrict__ W1_r,
                            const float* __restrict__ W2_l,
                            const float* __restrict__ W2_r,
                            _Float16* __restrict__ xf,
                            _Float16* __restrict__ B1,
                            _Float16* __restrict__ B2) {
    const int tid = blockIdx.x * 256 + threadIdx.x;      // < 800000
    {   // cast 4 floats -> 4 f16
        float4 v = *(const float4*)(x + tid * 4);
        H2U a, b;
        a.h = h2v{ (_Float16)v.x, (_Float16)v.y };
        b.h = h2v{ (_Float16)v.z, (_Float16)v.w };
        uint2 o = { a.u, b.u };
        *(uint2*)(xf + tid * 4) = o;
    }
    if (blockIdx.x == 0) {
        const int t = threadIdx.x;
        // B1: [W1_l; W1_r] (128 x 64), 16 frags (kt 0..3, nt 0..3)
        for (int p = t; p < 16 * 512; p += 256) {
            const int frag = p >> 9, lane = (p >> 3) & 63, j = p & 7;
            const int kt = frag >> 2, nt = frag & 3;
            const int k = kt * 32 + (lane >> 4) * 8 + j;
            const int n = nt * 16 + (lane & 15);
            const float w = (k < 64) ? W1_l[k * 64 + n] : W1_r[(k - 64) * 64 + n];
            B1[p] = (_Float16)w;
        }
        // B2: [W2_l | W2_r] (64 x 32), 4 frags (kt 0..1, nt 0..1)
        for (int p = t; p < 4 * 512; p += 256) {
            const int frag = p >> 9, lane = (p >> 3) & 63, j = p & 7;
            const int kt = frag >> 1, nt = frag & 1;
            const int k = kt * 32 + (lane >> 4) * 8 + j;
            const int n = lane & 15;
            const float w = (nt == 0) ? W2_l[k * 16 + n] : W2_r[k * 16 + n];
            B2[p] = (_Float16)w;
        }
    }
}

// ---------------------------------------------------------------------------
// Bin: partition edges into (bucket = dst>>7, shard = blockIdx&7) segments,
// packing (dst&127)<<16 | src into one word. 3128 append frontiers ->
// clustered writes; shard-by-blockIdx keeps frontier lines XCD-local.
// ---------------------------------------------------------------------------
__global__ void bin_kernel(const int* __restrict__ src,
                           const int* __restrict__ dst,
                           int* __restrict__ cntS,
                           int* __restrict__ bbuf) {
    const int e4 = blockIdx.x * 256 + threadIdx.x;
    if (e4 >= N_EDGES / 4) return;
    const int sh = blockIdx.x & 7;
    int4 s = *(const int4*)(src + e4 * 4);
    int4 d = *(const int4*)(dst + e4 * 4);
    #pragma unroll
    for (int q = 0; q < 4; ++q) {
        const int dv = (q == 0) ? d.x : (q == 1) ? d.y : (q == 2) ? d.z : d.w;
        const int sv = (q == 0) ? s.x : (q == 1) ? s.y : (q == 2) ? s.z : s.w;
        const int slot = (dv >> 7) * NSH + sh;
        const int p = atomicAdd(&cntS[slot], 1);
        if (p < CAP_S) bbuf[slot * CAP_S + p] = ((dv & 127) << 16) | sv;
    }
}

// ---------------------------------------------------------------------------
// Build: one workgroup per bucket. Coalesced read of the bucket's shards,
// LDS hist over 128 local nodes, LDS scan, LDS scatter, then fully-coalesced
// writes of the csr_src segment and rowptr range. Degrees fall out of hist;
// no global scan over 50K nodes anywhere.
// ---------------------------------------------------------------------------
__global__ __launch_bounds__(256) void build_kernel(
        const int* __restrict__ cntS,
        const int* __restrict__ bbuf,
        int* __restrict__ csr_src,
        int* __restrict__ rowptr) {
    __shared__ int stash[MAXB];
    __shared__ int lcsr[MAXB];
    __shared__ int hist[129];
    __shared__ int cur[128];
    __shared__ int red[256];

    const int b = blockIdx.x, t = threadIdx.x;

    // global base = total edges in buckets < b
    int part = 0;
    for (int i = t; i < b * NSH; i += 256) part += min(cntS[i], CAP_S);
    red[t] = part;
    if (t < 129) hist[t] = 0;
    __syncthreads();
    for (int off = 128; off > 0; off >>= 1) {
        if (t < off) red[t] += red[t + off];
        __syncthreads();
    }
    const int base = red[0];

    // load shards -> stash (compacted), LDS hist of local dst
    int off0 = 0;
    int cnt_b = 0;
    #pragma unroll
    for (int s = 0; s < NSH; ++s) {
        const int c = min(cntS[b * NSH + s], CAP_S);
        for (int i = t; i < c; i += 256) {
            const int w = bbuf[(b * NSH + s) * CAP_S + i];
            stash[off0 + i] = w;
            atomicAdd(&hist[w >> 16], 1);
        }
        off0 += c;
    }
    cnt_b = off0;
    __syncthreads();

    // exclusive scan of hist[0..127] (Hillis-Steele, 128 lanes)
    const int orig = (t < 128) ? hist[t] : 0;
    for (int off = 1; off < 128; off <<= 1) {
        int v = (t >= off && t < 128) ? hist[t - off] : 0;
        __syncthreads();
        if (t < 128) hist[t] += v;
        __syncthreads();
    }
    if (t < 128) cur[t] = hist[t] - orig;    // exclusive
    __syncthreads();

    // rowptr for this bucket's node range
    const int node = b * 128 + t;
    if (t < 128 && node < N_NODES) rowptr[node] = base + cur[t];
    if (b == NB - 1 && t == 0) rowptr[N_NODES] = base + cnt_b;

    // LDS scatter into local CSR order
    for (int i = t; i < cnt_b; i += 256) {
        const int w = stash[i];
        const int p = atomicAdd(&cur[w >> 16], 1);
        lcsr[p] = w & 0xFFFF;
    }
    __syncthreads();

    // coalesced write-out
    for (int i = t; i < cnt_b; i += 256) csr_src[base + i] = lcsr[i];
}

// ---------------------------------------------------------------------------
// Gather: one wave per node; c = l&7 (4 f16-pairs), g = l>>3 (8 neighbor
// groups). Row = 128B = one cacheline; v_pk_add_f16 accumulation; packed
// shfl reduce; mean written as f16 row.
// ---------------------------------------------------------------------------
__global__ __launch_bounds__(256) void gather_kernel(
        const _Float16* __restrict__ xf,
        const int* __restrict__ rowptr,
        const int* __restrict__ csr_src,
        _Float16* __restrict__ meanf) {
    const int n = blockIdx.x * 4 + (threadIdx.x >> 6);
    const int l = threadIdx.x & 63;
    const int c = l & 7;
    const int g = l >> 3;

    const int beg = rowptr[n];
    const int end = rowptr[n + 1];
    const int deg = end - beg;
    const int chunk = (deg + 7) >> 3;

    H2U a0, a1, a2, a3;
    a0.u = a1.u = a2.u = a3.u = 0;
    {
        int i = beg + g * chunk;
        const int ce = min(i + chunk, end);
        for (; i + 1 < ce; i += 2) {
            const int p = csr_src[i];
            const int q = csr_src[i + 1];
            uint4 up = *(const uint4*)(xf + p * 64 + c * 8);
            uint4 uq = *(const uint4*)(xf + q * 64 + c * 8);
            H2U t;
            t.u = up.x; a0.h += t.h;  t.u = uq.x; a0.h += t.h;
            t.u = up.y; a1.h += t.h;  t.u = uq.y; a1.h += t.h;
            t.u = up.z; a2.h += t.h;  t.u = uq.z; a2.h += t.h;
            t.u = up.w; a3.h += t.h;  t.u = uq.w; a3.h += t.h;
        }
        if (i < ce) {
            const int p = csr_src[i];
            uint4 up = *(const uint4*)(xf + p * 64 + c * 8);
            H2U t;
            t.u = up.x; a0.h += t.h;
            t.u = up.y; a1.h += t.h;
            t.u = up.z; a2.h += t.h;
            t.u = up.w; a3.h += t.h;
        }
    }
    #pragma unroll
    for (int off = 8; off <= 32; off <<= 1) {
        H2U r;
        r.u = (unsigned)__shfl_xor((int)a0.u, off); a0.h += r.h;
        r.u = (unsigned)__shfl_xor((int)a1.u, off); a1.h += r.h;
        r.u = (unsigned)__shfl_xor((int)a2.u, off); a2.h += r.h;
        r.u = (unsigned)__shfl_xor((int)a3.u, off); a3.h += r.h;
    }
    const float rdeg = 1.0f / fmaxf((float)deg, 1.0f);
    const _Float16 rh = (_Float16)rdeg;
    const h2v rd2 = { rh, rh };
    a0.h *= rd2; a1.h *= rd2; a2.h *= rd2; a3.h *= rd2;
    if (g == 0) {
        uint4 o = { a0.u, a1.u, a2.u, a3.u };
        *(uint4*)(meanf + n * 64 + c * 8) = o;
    }
}

// ---------------------------------------------------------------------------
// MLP via MFMA: one wave = 16 nodes. h = relu([mean|x]@[W1_l;W1_r] + b1)
// (16 MFMA), LDS round-trip into A-layout (stride 72 f16), then
// [y2|z] = h@[W2_l|W2_r] (4 MFMA). C/D: col=lane&15, row=(lane>>4)*4+reg.
// ---------------------------------------------------------------------------
__global__ __launch_bounds__(256) void mlp_kernel(
        const _Float16* __restrict__ xf,
        const _Float16* __restrict__ meanf,
        const _Float16* __restrict__ B1,
        const _Float16* __restrict__ B2,
        const float* __restrict__ b1,
        const float* __restrict__ b2,
        _Float16* __restrict__ y2f,
        float* __restrict__ z) {
    __shared__ _Float16 hlds[4][16 * 72];
    const int widx = threadIdx.x >> 6;
    const int l = threadIdx.x & 63;
    const int n0 = (blockIdx.x * 4 + widx) * 16;
    if (n0 >= N_NODES) return;                 // wave-uniform; no barriers used
    const int cn = l & 15;
    const int kq = l >> 4;

    h8v af[4];
    const _Float16* mrow = meanf + (n0 + cn) * 64 + kq * 8;
    af[0] = *(const h8v*)(mrow);
    af[1] = *(const h8v*)(mrow + 32);
    const _Float16* xrow = xf + (n0 + cn) * 64 + kq * 8;
    af[2] = *(const h8v*)(xrow);
    af[3] = *(const h8v*)(xrow + 32);

    const f4v zero = { 0.f, 0.f, 0.f, 0.f };
    f4v acc[4] = { zero, zero, zero, zero };
    #pragma unroll
    for (int nt = 0; nt < 4; ++nt) {
        #pragma unroll
        for (int kt = 0; kt < 4; ++kt) {
            h8v bf = *(const h8v*)(B1 + ((kt * 4 + nt) * 64 + l) * 8);
            acc[nt] = __builtin_amdgcn_mfma_f32_16x16x32_f16(af[kt], bf, acc[nt], 0, 0, 0);
        }
    }

    _Float16* hl = &hlds[widx][0];
    #pragma unroll
    for (int nt = 0; nt < 4; ++nt) {
        const float bias = b1[nt * 16 + cn];
        #pragma unroll
        for (int r = 0; r < 4; ++r) {
            const float hv = fmaxf(acc[nt][r] + bias, 0.f);
            hl[(kq * 4 + r) * 72 + nt * 16 + cn] = (_Float16)hv;
        }
    }

    h8v a2[2];
    a2[0] = *(const h8v*)(hl + cn * 72 + kq * 8);
    a2[1] = *(const h8v*)(hl + cn * 72 + 32 + kq * 8);
    f4v acc2[2] = { zero, zero };
    #pragma unroll
    for (int nt = 0; nt < 2; ++nt) {
        #pragma unroll
        for (int kt = 0; kt < 2; ++kt) {
            h8v bf = *(const h8v*)(B2 + ((kt * 2 + nt) * 64 + l) * 8);
            acc2[nt] = __builtin_amdgcn_mfma_f32_16x16x32_f16(a2[kt], bf, acc2[nt], 0, 0, 0);
        }
    }
    const float bz = b2[cn];
    #pragma unroll
    for (int r = 0; r < 4; ++r) {
        const int row = n0 + kq * 4 + r;
        y2f[row * 16 + cn] = (_Float16)acc2[0][r];
        z[row * 16 + cn] = acc2[1][r] + bz;
    }
}

// ---------------------------------------------------------------------------
// Layer 2: gather-mean of f16 y2 (32B rows; c2 = t&1 half, p2 = t>>1 slot;
// 4 nodes/wave) with packed-f16 accumulation, + z -> out.
// ---------------------------------------------------------------------------
__global__ __launch_bounds__(256) void layer2_kernel(
        const _Float16* __restrict__ y2f,
        const float* __restrict__ z,
        const int* __restrict__ rowptr,
        const int* __restrict__ csr_src,
        float* __restrict__ out) {
    const int wv = blockIdx.x * 4 + (threadIdx.x >> 6);
    const int l = threadIdx.x & 63;
    const int n = wv * 4 + (l >> 4);
    const int t = l & 15;
    const int c2 = t & 1;
    const int p2 = t >> 1;

    const int beg = rowptr[n];
    const int end = rowptr[n + 1];
    const int deg = end - beg;
    const int chunk = (deg + 7) >> 3;

    H2U a0, a1, a2, a3;
    a0.u = a1.u = a2.u = a3.u = 0;
    {
        int i = beg + p2 * chunk;
        const int ce = min(i + chunk, end);
        for (; i + 1 < ce; i += 2) {
            const int p = csr_src[i];
            const int q = csr_src[i + 1];
            uint4 up = *(const uint4*)(y2f + p * 16 + c2 * 8);
            uint4 uq = *(const uint4*)(y2f + q * 16 + c2 * 8);
            H2U r;
            r.u = up.x; a0.h += r.h;  r.u = uq.x; a0.h += r.h;
            r.u = up.y; a1.h += r.h;  r.u = uq.y; a1.h += r.h;
            r.u = up.z; a2.h += r.h;  r.u = uq.z; a2.h += r.h;
            r.u = up.w; a3.h += r.h;  r.u = uq.w; a3.h += r.h;
        }
        if (i < ce) {
            const int p = csr_src[i];
            uint4 up = *(const uint4*)(y2f + p * 16 + c2 * 8);
            H2U r;
            r.u = up.x; a0.h += r.h;
            r.u = up.y; a1.h += r.h;
            r.u = up.z; a2.h += r.h;
            r.u = up.w; a3.h += r.h;
        }
    }
    #pragma unroll
    for (int off = 2; off <= 8; off <<= 1) {
        H2U r;
        r.u = (unsigned)__shfl_xor((int)a0.u, off); a0.h += r.h;
        r.u = (unsigned)__shfl_xor((int)a1.u, off); a1.h += r.h;
        r.u = (unsigned)__shfl_xor((int)a2.u, off); a2.h += r.h;
        r.u = (unsigned)__shfl_xor((int)a3.u, off); a3.h += r.h;
    }
    if (p2 == 0) {
        const float rdeg = 1.0f / fmaxf((float)deg, 1.0f);
        const float4 z0 = *(const float4*)(z + n * 16 + c2 * 8);
        const float4 z1 = *(const float4*)(z + n * 16 + c2 * 8 + 4);
        float4 o0 = { (float)a0.h[0] * rdeg + z0.x, (float)a0.h[1] * rdeg + z0.y,
                      (float)a1.h[0] * rdeg + z0.z, (float)a1.h[1] * rdeg + z0.w };
        float4 o1 = { (float)a2.h[0] * rdeg + z1.x, (float)a2.h[1] * rdeg + z1.y,
                      (float)a3.h[0] * rdeg + z1.z, (float)a3.h[1] * rdeg + z1.w };
        *(float4*)(out + n * 16 + c2 * 8) = o0;
        *(float4*)(out + n * 16 + c2 * 8 + 4) = o1;
    }
}

extern "C" void kernel_launch(void* const* d_in, const int* in_sizes, int n_in,
                              void* d_out, int out_size, void* d_ws, size_t ws_size,
                              hipStream_t stream) {
    const float* x    = (const float*)d_in[0];
    const int*   ei   = (const int*)d_in[1];   // [2, 800000]: row 0 = src, row 1 = dst
    const float* W1_l = (const float*)d_in[2];
    const float* b1   = (const float*)d_in[3];
    const float* W1_r = (const float*)d_in[4];
    const float* W2_l = (const float*)d_in[5];
    const float* b2   = (const float*)d_in[6];
    const float* W2_r = (const float*)d_in[7];
    float* out = (float*)d_out;

    const int* src = ei;
    const int* dst = ei + N_EDGES;

    // Workspace layout (4-byte units):
    int* ws = (int*)d_ws;
    int*   cntS    = ws;                              // NB*NSH = 3128 (pad 3136)
    int*   rowptr  = cntS + 3136;                     // 50001 (pad 50056)
    int*   bbuf    = rowptr + 50056;                  // NB*NSH*CAP_S = 1,601,536
    int*   csr_src = bbuf + NB * NSH * CAP_S;         // 800,000
    _Float16* xf    = (_Float16*)(csr_src + 800000);  // 3,200,000 f16
    _Float16* meanf = xf + 3200000;                   // 3,200,000 f16
    _Float16* B1    = meanf + 3200000;                // 8,192 f16
    _Float16* B2    = B1 + 8192;                      // 2,048 f16
    _Float16* y2f   = B2 + 2048;                      // 800,000 f16
    float*    z     = (float*)(y2f + 800000);         // 800,000 f32
    // total ~25 MB

    hipMemsetAsync(cntS, 0, 3136 * sizeof(int), stream);

    prep_kernel<<<3125, 256, 0, stream>>>(x, W1_l, W1_r, W2_l, W2_r, xf, B1, B2);
    bin_kernel<<<(N_EDGES / 4 + 255) / 256, 256, 0, stream>>>(src, dst, cntS, bbuf);
    build_kernel<<<NB, 256, 0, stream>>>(cntS, bbuf, csr_src, rowptr);
    gather_kernel<<<N_NODES / 4, 256, 0, stream>>>(xf, rowptr, csr_src, meanf);
    mlp_kernel<<<(N_NODES / 16 + 3) / 4, 256, 0, stream>>>(xf, meanf, B1, B2,
                                                           b1, b2, y2f, z);
    layer2_kernel<<<N_NODES / 16, 256, 0, stream>>>(y2f, z, rowptr, csr_src, out);
}

// Round 9
// 145.160 us; speedup vs baseline: 1.4503x; 1.4503x over previous
//
#include <hip/hip_runtime.h>

#define N_NODES 50000
#define N_EDGES 800000
#define NB      391            // buckets: dst>>7 (128 nodes each)
#define NBP     392            // padded bucket count (pad col stays zero)
#define G       128            // partition blocks for count/scatter
#define SCAN_N  (NBP * G)      // 50176 = 49 * 1024
#define SCAN_BLOCKS 49
#define MAXB    3072           // max edges per bucket (mean 2046, sigma ~45)

typedef _Float16 h2v __attribute__((ext_vector_type(2)));
typedef _Float16 h8v __attribute__((ext_vector_type(8)));
typedef float    f4v __attribute__((ext_vector_type(4)));

union H2U { h2v h; unsigned u; };   // packed f16 pair <-> dword

// ---------------------------------------------------------------------------
// Prep: cast x -> f16 + pack W1/W2 into MFMA B-fragment order (block 0 only).
// B-frag (16x16x32 f16): lane holds 8 f16 B[k=32kt+(lane>>4)*8+j][n=16nt+(lane&15)].
// ---------------------------------------------------------------------------
__global__ void prep_kernel(const float* __restrict__ x,
                            const float* __restrict__ W1_l,
                            const float* __restrict__ W1_r,
                            const float* __restrict__ W2_l,
                            const float* __restrict__ W2_r,
                            _Float16* __restrict__ xf,
                            _Float16* __restrict__ B1,
                            _Float16* __restrict__ B2) {
    const int tid = blockIdx.x * 256 + threadIdx.x;      // < 800000
    {   // cast 4 floats -> 4 f16
        float4 v = *(const float4*)(x + tid * 4);
        H2U a, b;
        a.h = h2v{ (_Float16)v.x, (_Float16)v.y };
        b.h = h2v{ (_Float16)v.z, (_Float16)v.w };
        uint2 o = { a.u, b.u };
        *(uint2*)(xf + tid * 4) = o;
    }
    if (blockIdx.x == 0) {
        const int t = threadIdx.x;
        // B1: [W1_l; W1_r] (128 x 64), 16 frags (kt 0..3, nt 0..3)
        for (int p = t; p < 16 * 512; p += 256) {
            const int frag = p >> 9, lane = (p >> 3) & 63, j = p & 7;
            const int kt = frag >> 2, nt = frag & 3;
            const int k = kt * 32 + (lane >> 4) * 8 + j;
            const int n = nt * 16 + (lane & 15);
            const float w = (k < 64) ? W1_l[k * 64 + n] : W1_r[(k - 64) * 64 + n];
            B1[p] = (_Float16)w;
        }
        // B2: [W2_l | W2_r] (64 x 32), 4 frags (kt 0..1, nt 0..1)
        for (int p = t; p < 4 * 512; p += 256) {
            const int frag = p >> 9, lane = (p >> 3) & 63, j = p & 7;
            const int kt = frag >> 1, nt = frag & 1;
            const int k = kt * 32 + (lane >> 4) * 8 + j;
            const int n = lane & 15;
            const float w = (nt == 0) ? W2_l[k * 16 + n] : W2_r[k * 16 + n];
            B2[p] = (_Float16)w;
        }
    }
}

// ---------------------------------------------------------------------------
// Partition pass 1: per-block LDS histogram of dst buckets (LDS atomics only),
// coalesced write to histG[block][bucket]. Block b owns int4 indices
// {b*512+t + k*65536} — same strided partition as scatter_kernel.
// ---------------------------------------------------------------------------
__global__ __launch_bounds__(512) void count_kernel(const int* __restrict__ dst,
                                                    int* __restrict__ histG) {
    __shared__ int hist[NBP];
    const int b = blockIdx.x, t = threadIdx.x;
    for (int i = t; i < NBP; i += 512) hist[i] = 0;
    __syncthreads();
    for (int i4 = b * 512 + t; i4 < N_EDGES / 4; i4 += G * 512) {
        int4 d = *(const int4*)(dst + i4 * 4);
        atomicAdd(&hist[d.x >> 7], 1);
        atomicAdd(&hist[d.y >> 7], 1);
        atomicAdd(&hist[d.z >> 7], 1);
        atomicAdd(&hist[d.w >> 7], 1);
    }
    __syncthreads();
    for (int i = t; i < NB; i += 512) histG[b * NBP + i] = hist[i];
}

// ---------------------------------------------------------------------------
// Scan step A over the TRANSPOSED histogram (bucket-major linear index
// i = bucket*G + blk -> histG[blk*NBP + bucket]). 49 blocks x 1024 elems.
// ---------------------------------------------------------------------------
__global__ void scanA_kernel(const int* __restrict__ histG,
                             int* __restrict__ loc,
                             int* __restrict__ bsum) {
    __shared__ int lds[256];
    const int b = blockIdx.x, t = threadIdx.x;
    const int base = b * 1024 + t * 4;
    int v[4];
    #pragma unroll
    for (int q = 0; q < 4; ++q) {
        const int i = base + q;
        v[q] = histG[(i & (G - 1)) * NBP + (i >> 7)];
    }
    const int s = v[0] + v[1] + v[2] + v[3];
    lds[t] = s;
    __syncthreads();
    for (int off = 1; off < 256; off <<= 1) {
        int u = (t >= off) ? lds[t - off] : 0;
        __syncthreads();
        lds[t] += u;
        __syncthreads();
    }
    const int excl = lds[t] - s;
    int4 o;
    o.x = excl;
    o.y = excl + v[0];
    o.z = excl + v[0] + v[1];
    o.w = excl + v[0] + v[1] + v[2];
    *(int4*)(loc + base) = o;
    if (t == 255) bsum[b] = lds[255];
}

// ---------------------------------------------------------------------------
// Scan step C: every wave shfl-scans the 49 block sums, adds offset, emits
// offT (exact global base per (bucket, block)). No cursor needed.
// ---------------------------------------------------------------------------
__global__ void scanC_kernel(const int* __restrict__ loc,
                             const int* __restrict__ bsum,
                             int* __restrict__ offT) {
    const int b = blockIdx.x, t = threadIdx.x;
    const int lane = t & 63;
    int v = (lane < SCAN_BLOCKS) ? bsum[lane] : 0;
    for (int off = 1; off < 64; off <<= 1) {
        int u = __shfl_up(v, off);
        if (lane >= off) v += u;
    }
    const int boff = (b == 0) ? 0 : __shfl(v, b - 1);
    const int base = b * 1024 + t * 4;
    int4 w = *(const int4*)(loc + base);
    w.x += boff; w.y += boff; w.z += boff; w.w += boff;
    *(int4*)(offT + base) = w;
}

// ---------------------------------------------------------------------------
// Partition pass 2: scatter edges to exact positions. cur[bucket] seeded from
// offT[bucket*G + b]; LDS atomicAdd gives the global slot — ZERO global
// atomics. Stores land in per-(bucket,block) runs (~50 consecutive words).
// Packs (dst&127)<<16 | src (src < 65536? no — src < 50000 < 65536 OK).
// ---------------------------------------------------------------------------
__global__ __launch_bounds__(512) void scatter_kernel(const int* __restrict__ src,
                                                      const int* __restrict__ dst,
                                                      const int* __restrict__ offT,
                                                      int* __restrict__ bbuf) {
    __shared__ int cur[NB];
    const int b = blockIdx.x, t = threadIdx.x;
    for (int i = t; i < NB; i += 512) cur[i] = offT[i * G + b];
    __syncthreads();
    for (int i4 = b * 512 + t; i4 < N_EDGES / 4; i4 += G * 512) {
        int4 s = *(const int4*)(src + i4 * 4);
        int4 d = *(const int4*)(dst + i4 * 4);
        #pragma unroll
        for (int q = 0; q < 4; ++q) {
            const int dv = (q == 0) ? d.x : (q == 1) ? d.y : (q == 2) ? d.z : d.w;
            const int sv = (q == 0) ? s.x : (q == 1) ? s.y : (q == 2) ? s.z : s.w;
            const int pos = atomicAdd(&cur[dv >> 7], 1);
            bbuf[pos] = ((dv & 127) << 16) | sv;
        }
    }
}

// ---------------------------------------------------------------------------
// Build: one workgroup per bucket. Contiguous read of the bucket's packed
// edges, LDS hist over 128 local nodes, LDS scan -> rowptr, LDS scatter,
// fully-coalesced csr_src write-out.
// ---------------------------------------------------------------------------
__global__ __launch_bounds__(256) void build_kernel(
        const int* __restrict__ offT,
        const int* __restrict__ bbuf,
        int* __restrict__ csr_src,
        int* __restrict__ rowptr) {
    __shared__ int stash[MAXB];
    __shared__ int lcsr[MAXB];
    __shared__ int hist[128];
    __shared__ int cur[128];

    const int b = blockIdx.x, t = threadIdx.x;
    const int start = offT[b * G];
    const int end = offT[(b + 1) * G];     // valid for b=NB-1 via pad bucket
    const int cnt_b = min(end - start, MAXB);

    if (t < 128) hist[t] = 0;
    __syncthreads();

    for (int i = t; i < cnt_b; i += 256) {
        const int w = bbuf[start + i];
        stash[i] = w;
        atomicAdd(&hist[w >> 16], 1);
    }
    __syncthreads();

    // exclusive scan of hist[0..127]
    const int orig = (t < 128) ? hist[t] : 0;
    for (int off = 1; off < 128; off <<= 1) {
        int v = (t >= off && t < 128) ? hist[t - off] : 0;
        __syncthreads();
        if (t < 128) hist[t] += v;
        __syncthreads();
    }
    if (t < 128) cur[t] = hist[t] - orig;    // exclusive
    __syncthreads();

    const int node = b * 128 + t;
    if (t < 128 && node < N_NODES) rowptr[node] = start + cur[t];
    if (b == NB - 1 && t == 0) rowptr[N_NODES] = N_EDGES;

    for (int i = t; i < cnt_b; i += 256) {
        const int w = stash[i];
        const int p = atomicAdd(&cur[w >> 16], 1);
        lcsr[p] = w & 0xFFFF;
    }
    __syncthreads();

    for (int i = t; i < cnt_b; i += 256) csr_src[start + i] = lcsr[i];
}

// ---------------------------------------------------------------------------
// Gather: one wave per node; c = l&7 (4 f16-pairs), g = l>>3 (8 neighbor
// groups). Row = 128B = one cacheline; v_pk_add_f16 accumulation; packed
// shfl reduce; mean written as f16 row.
// ---------------------------------------------------------------------------
__global__ __launch_bounds__(256) void gather_kernel(
        const _Float16* __restrict__ xf,
        const int* __restrict__ rowptr,
        const int* __restrict__ csr_src,
        _Float16* __restrict__ meanf) {
    const int n = blockIdx.x * 4 + (threadIdx.x >> 6);
    const int l = threadIdx.x & 63;
    const int c = l & 7;
    const int g = l >> 3;

    const int beg = rowptr[n];
    const int end = rowptr[n + 1];
    const int deg = end - beg;
    const int chunk = (deg + 7) >> 3;

    H2U a0, a1, a2, a3;
    a0.u = a1.u = a2.u = a3.u = 0;
    {
        int i = beg + g * chunk;
        const int ce = min(i + chunk, end);
        for (; i + 1 < ce; i += 2) {
            const int p = csr_src[i];
            const int q = csr_src[i + 1];
            uint4 up = *(const uint4*)(xf + p * 64 + c * 8);
            uint4 uq = *(const uint4*)(xf + q * 64 + c * 8);
            H2U t;
            t.u = up.x; a0.h += t.h;  t.u = uq.x; a0.h += t.h;
            t.u = up.y; a1.h += t.h;  t.u = uq.y; a1.h += t.h;
            t.u = up.z; a2.h += t.h;  t.u = uq.z; a2.h += t.h;
            t.u = up.w; a3.h += t.h;  t.u = uq.w; a3.h += t.h;
        }
        if (i < ce) {
            const int p = csr_src[i];
            uint4 up = *(const uint4*)(xf + p * 64 + c * 8);
            H2U t;
            t.u = up.x; a0.h += t.h;
            t.u = up.y; a1.h += t.h;
            t.u = up.z; a2.h += t.h;
            t.u = up.w; a3.h += t.h;
        }
    }
    #pragma unroll
    for (int off = 8; off <= 32; off <<= 1) {
        H2U r;
        r.u = (unsigned)__shfl_xor((int)a0.u, off); a0.h += r.h;
        r.u = (unsigned)__shfl_xor((int)a1.u, off); a1.h += r.h;
        r.u = (unsigned)__shfl_xor((int)a2.u, off); a2.h += r.h;
        r.u = (unsigned)__shfl_xor((int)a3.u, off); a3.h += r.h;
    }
    const float rdeg = 1.0f / fmaxf((float)deg, 1.0f);
    const _Float16 rh = (_Float16)rdeg;
    const h2v rd2 = { rh, rh };
    a0.h *= rd2; a1.h *= rd2; a2.h *= rd2; a3.h *= rd2;
    if (g == 0) {
        uint4 o = { a0.u, a1.u, a2.u, a3.u };
        *(uint4*)(meanf + n * 64 + c * 8) = o;
    }
}

// ---------------------------------------------------------------------------
// MLP via MFMA: one wave = 16 nodes. h = relu([mean|x]@[W1_l;W1_r] + b1)
// (16 MFMA), LDS round-trip into A-layout (stride 72 f16), then
// [y2|z] = h@[W2_l|W2_r] (4 MFMA). C/D: col=lane&15, row=(lane>>4)*4+reg.
// ---------------------------------------------------------------------------
__global__ __launch_bounds__(256) void mlp_kernel(
        const _Float16* __restrict__ xf,
        const _Float16* __restrict__ meanf,
        const _Float16* __restrict__ B1,
        const _Float16* __restrict__ B2,
        const float* __restrict__ b1,
        const float* __restrict__ b2,
        _Float16* __restrict__ y2f,
        float* __restrict__ z) {
    __shared__ _Float16 hlds[4][16 * 72];
    const int widx = threadIdx.x >> 6;
    const int l = threadIdx.x & 63;
    const int n0 = (blockIdx.x * 4 + widx) * 16;
    if (n0 >= N_NODES) return;                 // wave-uniform; no barriers used
    const int cn = l & 15;
    const int kq = l >> 4;

    h8v af[4];
    const _Float16* mrow = meanf + (n0 + cn) * 64 + kq * 8;
    af[0] = *(const h8v*)(mrow);
    af[1] = *(const h8v*)(mrow + 32);
    const _Float16* xrow = xf + (n0 + cn) * 64 + kq * 8;
    af[2] = *(const h8v*)(xrow);
    af[3] = *(const h8v*)(xrow + 32);

    const f4v zero = { 0.f, 0.f, 0.f, 0.f };
    f4v acc[4] = { zero, zero, zero, zero };
    #pragma unroll
    for (int nt = 0; nt < 4; ++nt) {
        #pragma unroll
        for (int kt = 0; kt < 4; ++kt) {
            h8v bf = *(const h8v*)(B1 + ((kt * 4 + nt) * 64 + l) * 8);
            acc[nt] = __builtin_amdgcn_mfma_f32_16x16x32_f16(af[kt], bf, acc[nt], 0, 0, 0);
        }
    }

    _Float16* hl = &hlds[widx][0];
    #pragma unroll
    for (int nt = 0; nt < 4; ++nt) {
        const float bias = b1[nt * 16 + cn];
        #pragma unroll
        for (int r = 0; r < 4; ++r) {
            const float hv = fmaxf(acc[nt][r] + bias, 0.f);
            hl[(kq * 4 + r) * 72 + nt * 16 + cn] = (_Float16)hv;
        }
    }

    h8v a2[2];
    a2[0] = *(const h8v*)(hl + cn * 72 + kq * 8);
    a2[1] = *(const h8v*)(hl + cn * 72 + 32 + kq * 8);
    f4v acc2[2] = { zero, zero };
    #pragma unroll
    for (int nt = 0; nt < 2; ++nt) {
        #pragma unroll
        for (int kt = 0; kt < 2; ++kt) {
            h8v bf = *(const h8v*)(B2 + ((kt * 2 + nt) * 64 + l) * 8);
            acc2[nt] = __builtin_amdgcn_mfma_f32_16x16x32_f16(a2[kt], bf, acc2[nt], 0, 0, 0);
        }
    }
    const float bz = b2[cn];
    #pragma unroll
    for (int r = 0; r < 4; ++r) {
        const int row = n0 + kq * 4 + r;
        y2f[row * 16 + cn] = (_Float16)acc2[0][r];
        z[row * 16 + cn] = acc2[1][r] + bz;
    }
}

// ---------------------------------------------------------------------------
// Layer 2: gather-mean of f16 y2 (32B rows; c2 = t&1 half, p2 = t>>1 slot;
// 4 nodes/wave) with packed-f16 accumulation, + z -> out.
// ---------------------------------------------------------------------------
__global__ __launch_bounds__(256) void layer2_kernel(
        const _Float16* __restrict__ y2f,
        const float* __restrict__ z,
        const int* __restrict__ rowptr,
        const int* __restrict__ csr_src,
        float* __restrict__ out) {
    const int wv = blockIdx.x * 4 + (threadIdx.x >> 6);
    const int l = threadIdx.x & 63;
    const int n = wv * 4 + (l >> 4);
    const int t = l & 15;
    const int c2 = t & 1;
    const int p2 = t >> 1;

    const int beg = rowptr[n];
    const int end = rowptr[n + 1];
    const int deg = end - beg;
    const int chunk = (deg + 7) >> 3;

    H2U a0, a1, a2, a3;
    a0.u = a1.u = a2.u = a3.u = 0;
    {
        int i = beg + p2 * chunk;
        const int ce = min(i + chunk, end);
        for (; i + 1 < ce; i += 2) {
            const int p = csr_src[i];
            const int q = csr_src[i + 1];
            uint4 up = *(const uint4*)(y2f + p * 16 + c2 * 8);
            uint4 uq = *(const uint4*)(y2f + q * 16 + c2 * 8);
            H2U r;
            r.u = up.x; a0.h += r.h;  r.u = uq.x; a0.h += r.h;
            r.u = up.y; a1.h += r.h;  r.u = uq.y; a1.h += r.h;
            r.u = up.z; a2.h += r.h;  r.u = uq.z; a2.h += r.h;
            r.u = up.w; a3.h += r.h;  r.u = uq.w; a3.h += r.h;
        }
        if (i < ce) {
            const int p = csr_src[i];
            uint4 up = *(const uint4*)(y2f + p * 16 + c2 * 8);
            H2U r;
            r.u = up.x; a0.h += r.h;
            r.u = up.y; a1.h += r.h;
            r.u = up.z; a2.h += r.h;
            r.u = up.w; a3.h += r.h;
        }
    }
    #pragma unroll
    for (int off = 2; off <= 8; off <<= 1) {
        H2U r;
        r.u = (unsigned)__shfl_xor((int)a0.u, off); a0.h += r.h;
        r.u = (unsigned)__shfl_xor((int)a1.u, off); a1.h += r.h;
        r.u = (unsigned)__shfl_xor((int)a2.u, off); a2.h += r.h;
        r.u = (unsigned)__shfl_xor((int)a3.u, off); a3.h += r.h;
    }
    if (p2 == 0) {
        const float rdeg = 1.0f / fmaxf((float)deg, 1.0f);
        const float4 z0 = *(const float4*)(z + n * 16 + c2 * 8);
        const float4 z1 = *(const float4*)(z + n * 16 + c2 * 8 + 4);
        float4 o0 = { (float)a0.h[0] * rdeg + z0.x, (float)a0.h[1] * rdeg + z0.y,
                      (float)a1.h[0] * rdeg + z0.z, (float)a1.h[1] * rdeg + z0.w };
        float4 o1 = { (float)a2.h[0] * rdeg + z1.x, (float)a2.h[1] * rdeg + z1.y,
                      (float)a3.h[0] * rdeg + z1.z, (float)a3.h[1] * rdeg + z1.w };
        *(float4*)(out + n * 16 + c2 * 8) = o0;
        *(float4*)(out + n * 16 + c2 * 8 + 4) = o1;
    }
}

extern "C" void kernel_launch(void* const* d_in, const int* in_sizes, int n_in,
                              void* d_out, int out_size, void* d_ws, size_t ws_size,
                              hipStream_t stream) {
    const float* x    = (const float*)d_in[0];
    const int*   ei   = (const int*)d_in[1];   // [2, 800000]: row 0 = src, row 1 = dst
    const float* W1_l = (const float*)d_in[2];
    const float* b1   = (const float*)d_in[3];
    const float* W1_r = (const float*)d_in[4];
    const float* W2_l = (const float*)d_in[5];
    const float* b2   = (const float*)d_in[6];
    const float* W2_r = (const float*)d_in[7];
    float* out = (float*)d_out;

    const int* src = ei;
    const int* dst = ei + N_EDGES;

    // Workspace layout (4-byte units):
    int* ws = (int*)d_ws;
    int*   histG   = ws;                              // SCAN_N = 50176
    int*   loc     = histG + SCAN_N;                  // 50176
    int*   offT    = loc   + SCAN_N;                  // 50176
    int*   bsum    = offT  + SCAN_N;                  // 64
    int*   rowptr  = bsum  + 64;                      // 50001 (pad 50056)
    int*   bbuf    = rowptr + 50056;                  // 800,000 packed edges
    int*   csr_src = bbuf + 800000;                   // 800,000
    _Float16* xf    = (_Float16*)(csr_src + 800000);  // 3,200,000 f16
    _Float16* meanf = xf + 3200000;                   // 3,200,000 f16
    _Float16* B1    = meanf + 3200000;                // 8,192 f16
    _Float16* B2    = B1 + 8192;                      // 2,048 f16
    _Float16* y2f   = B2 + 2048;                      // 800,000 f16
    float*    z     = (float*)(y2f + 800000);         // 800,000 f32
    // total ~25 MB

    hipMemsetAsync(histG, 0, SCAN_N * sizeof(int), stream);

    prep_kernel<<<3125, 256, 0, stream>>>(x, W1_l, W1_r, W2_l, W2_r, xf, B1, B2);
    count_kernel<<<G, 512, 0, stream>>>(dst, histG);
    scanA_kernel<<<SCAN_BLOCKS, 256, 0, stream>>>(histG, loc, bsum);
    scanC_kernel<<<SCAN_BLOCKS, 256, 0, stream>>>(loc, bsum, offT);
    scatter_kernel<<<G, 512, 0, stream>>>(src, dst, offT, bbuf);
    build_kernel<<<NB, 256, 0, stream>>>(offT, bbuf, csr_src, rowptr);
    gather_kernel<<<N_NODES / 4, 256, 0, stream>>>(xf, rowptr, csr_src, meanf);
    mlp_kernel<<<(N_NODES / 16 + 3) / 4, 256, 0, stream>>>(xf, meanf, B1, B2,
                                                           b1, b2, y2f, z);
    layer2_kernel<<<N_NODES / 16, 256, 0, stream>>>(y2f, z, rowptr, csr_src, out);
}